// Round 1
// baseline (1009.767 us; speedup 1.0000x reference)
//
#include <hip/hip_runtime.h>

#define CIN   256
#define COUT  256
#define Hh    64
#define Ww    64
#define Bb    4
#define KKN   9
#define KDIM  2304   // CIN*9
#define HW    4096   // 64*64
#define CCHUNK 8
#define KSTEPS (CCHUNK * KKN)   // 72

// ---------------------------------------------------------------------------
// Kernel 1: offset conv  (4,256,64,64) x (18,256,3,3) + bias -> (4,18,64,64)
// One thread per output element. x loads coalesced over wo; weights wave-
// uniform (oc,ho,b uniform within wave) -> scalar loads.
// ---------------------------------------------------------------------------
__global__ __launch_bounds__(256) void offset_conv_kernel(
    const float* __restrict__ x, const float* __restrict__ ow,
    const float* __restrict__ ob, float* __restrict__ offset) {
  int flat = blockIdx.x * 256 + threadIdx.x;   // b*18*4096 + oc*4096 + ho*64 + wo
  int wo = flat & 63;
  int ho = (flat >> 6) & 63;
  int oc = (flat >> 12) % 18;
  int b  = flat / (18 * HW);
  float acc = ob[oc];
  const float* xb   = x + (size_t)b * CIN * HW;
  const float* wrow = ow + (size_t)oc * CIN * 9;
  #pragma unroll
  for (int ky = 0; ky < 3; ++ky) {
    int y = ho - 1 + ky;
    if (y < 0 || y >= Hh) continue;
    #pragma unroll
    for (int kx = 0; kx < 3; ++kx) {
      int xc = wo - 1 + kx;
      if (xc < 0 || xc >= Ww) continue;
      const float* xp = xb + y * Ww + xc;
      const float* wp = wrow + ky * 3 + kx;
      for (int c = 0; c < CIN; ++c) {
        acc = fmaf(xp[(size_t)c * HW], wp[(size_t)c * 9], acc);
      }
    }
  }
  offset[flat] = acc;
}

// ---------------------------------------------------------------------------
// Kernel 2: transpose weight (COUT, CIN*9) -> wT (CIN*9, COUT) so the main
// kernel's weight row per K-step is contiguous (enables s_load_dwordx batches).
// ---------------------------------------------------------------------------
__global__ __launch_bounds__(256) void transpose_w_kernel(
    const float* __restrict__ w, float* __restrict__ wT) {
  int idx = blockIdx.x * 256 + threadIdx.x;  // k*256 + oc ; total KDIM*COUT
  int oc = idx & 255;
  int k  = idx >> 8;
  wT[idx] = w[(size_t)oc * KDIM + k];
}

// ---------------------------------------------------------------------------
// Kernel 3: fused bilinear sampling + implicit GEMM.
// Block = (b, ho): 64 pixels x 256 oc. 256 threads = 4 waves; each wave owns
// a 64-oc group; thread's pixel = lane. acc[64] per thread.
// ---------------------------------------------------------------------------
__global__ __launch_bounds__(256) void deform_main_kernel(
    const float* __restrict__ x, const float* __restrict__ offset,
    const float* __restrict__ wT, float* __restrict__ out) {
  __shared__ int4   sm_idx[KKN][64];           // 4 clamped gather indices
  __shared__ float4 sm_w[KKN][64];             // 4 mask-folded bilinear weights
  __shared__ float  sm_samp[KSTEPS][64];       // staged samples for one chunk

  const int tid = threadIdx.x;
  const int blk = blockIdx.x;     // b*64 + ho
  const int ho  = blk & 63;
  const int b   = blk >> 6;
  const int p   = tid & 63;       // pixel (= wo)
  const int ocg = tid >> 6;       // 0..3 oc-group

  // ---- Phase 0: bilinear metadata for 9*64 (kk, pixel) pairs ----
  const float* offb = offset + (size_t)b * 18 * HW + (size_t)ho * Ww;
  for (int i = tid; i < KKN * 64; i += 256) {
    int pp = i & 63;
    int kk = i >> 6;
    int ky = kk / 3, kx = kk % 3;
    float dy = offb[(size_t)(2 * kk) * HW + pp];
    float dx = offb[(size_t)(2 * kk + 1) * HW + pp];
    float py = (float)(ho - 1 + ky) + dy;
    float px = (float)(pp - 1 + kx) + dx;
    float y0f = floorf(py), x0f = floorf(px);
    int y0 = (int)y0f, x0 = (int)x0f;
    float wy1 = py - y0f, wy0 = 1.0f - wy1;
    float wx1 = px - x0f, wx0 = 1.0f - wx1;
    int4 idx4; float4 w4;
    {
      int yy = y0, xx = x0;
      bool v = (yy >= 0 && yy < Hh && xx >= 0 && xx < Ww);
      idx4.x = min(max(yy, 0), Hh - 1) * Ww + min(max(xx, 0), Ww - 1);
      w4.x = v ? (wy0 * wx0) : 0.0f;
    }
    {
      int yy = y0, xx = x0 + 1;
      bool v = (yy >= 0 && yy < Hh && xx >= 0 && xx < Ww);
      idx4.y = min(max(yy, 0), Hh - 1) * Ww + min(max(xx, 0), Ww - 1);
      w4.y = v ? (wy0 * wx1) : 0.0f;
    }
    {
      int yy = y0 + 1, xx = x0;
      bool v = (yy >= 0 && yy < Hh && xx >= 0 && xx < Ww);
      idx4.z = min(max(yy, 0), Hh - 1) * Ww + min(max(xx, 0), Ww - 1);
      w4.z = v ? (wy1 * wx0) : 0.0f;
    }
    {
      int yy = y0 + 1, xx = x0 + 1;
      bool v = (yy >= 0 && yy < Hh && xx >= 0 && xx < Ww);
      idx4.w = min(max(yy, 0), Hh - 1) * Ww + min(max(xx, 0), Ww - 1);
      w4.w = v ? (wy1 * wx1) : 0.0f;
    }
    sm_idx[kk][pp] = idx4;
    sm_w[kk][pp]   = w4;
  }
  __syncthreads();

  float acc[64];
  #pragma unroll
  for (int i = 0; i < 64; ++i) acc[i] = 0.0f;

  const float* xb = x + (size_t)b * CIN * HW;
  const int ocg_u = __builtin_amdgcn_readfirstlane(ocg);

  for (int c0 = 0; c0 < CIN; c0 += CCHUNK) {
    __syncthreads();  // sm_samp reuse guard (prev chunk's FMA phase done)
    // ---- stage samples: 72 K-steps x 64 pixels, 18 per thread ----
    for (int i = tid; i < KSTEPS * 64; i += 256) {
      int pp = i & 63;
      int t  = i >> 6;             // 0..71 = c_local*9 + kk
      int kk = t % 9;
      int cl = t / 9;
      const float* xp = xb + (size_t)(c0 + cl) * HW;
      int4   ip = sm_idx[kk][pp];
      float4 wp = sm_w[kk][pp];
      float v = xp[ip.x] * wp.x + xp[ip.y] * wp.y +
                xp[ip.z] * wp.z + xp[ip.w] * wp.w;
      sm_samp[t][pp] = v;
    }
    __syncthreads();
    // ---- FMA phase: 72 K-steps, 64 oc each ----
    const float* wbase = wT + (size_t)(c0 * 9) * COUT + ocg_u * 64;
    for (int t = 0; t < KSTEPS; ++t) {
      float sv = sm_samp[t][p];                 // ds_read_b32, conflict-free
      const float* wrow = wbase + (size_t)t * COUT;  // wave-uniform -> s_load
      #pragma unroll
      for (int i = 0; i < 64; ++i)
        acc[i] = fmaf(sv, wrow[i], acc[i]);
    }
  }

  // ---- epilogue: out[b][ocg*64+i][ho][p], coalesced over lanes ----
  float* obp = out + ((size_t)b * COUT + (size_t)ocg * 64) * HW +
               (size_t)ho * Ww + p;
  #pragma unroll
  for (int i = 0; i < 64; ++i)
    obp[(size_t)i * HW] = acc[i];
}

// ---------------------------------------------------------------------------
extern "C" void kernel_launch(void* const* d_in, const int* in_sizes, int n_in,
                              void* d_out, int out_size, void* d_ws, size_t ws_size,
                              hipStream_t stream) {
  const float* x  = (const float*)d_in[0];   // (4,256,64,64)
  const float* ow = (const float*)d_in[1];   // (18,256,3,3)
  const float* ob = (const float*)d_in[2];   // (18,)
  const float* w  = (const float*)d_in[3];   // (256,256,3,3)
  float* out = (float*)d_out;                // (4,256,64,64)

  float* offset = (float*)d_ws;              // 4*18*4096 floats = 1.18 MB
  float* wT     = offset + (size_t)Bb * 18 * HW;  // 2304*256 floats = 2.36 MB

  hipLaunchKernelGGL(offset_conv_kernel, dim3((Bb * 18 * HW) / 256), dim3(256),
                     0, stream, x, ow, ob, offset);
  hipLaunchKernelGGL(transpose_w_kernel, dim3((KDIM * COUT) / 256), dim3(256),
                     0, stream, w, wT);
  hipLaunchKernelGGL(deform_main_kernel, dim3(Bb * Hh), dim3(256),
                     0, stream, x, offset, wT, out);
}

// Round 3
// 526.180 us; speedup vs baseline: 1.9191x; 1.9191x over previous
//
#include <hip/hip_runtime.h>

#define CIN   256
#define COUT  256
#define Hh    64
#define Ww    64
#define Bb    4
#define HW    4096
#define KDIM  2304        // CIN*9
#define CCHUNK 8
#define KSTEPS (CCHUNK * 9)   // 72
#define MT    32          // pixels per main-kernel block (half row)

// ---------------------------------------------------------------------------
// Kernel 1: offset conv  (4,256,64,64) x (18,256,3,3) + bias -> (4,18,64,64)
// Block = (b, ho) row: 256 threads = 4 waves; wave w owns channels 64w..64w+63,
// lane = pixel. Per-thread acc[18] in regs (static indexing). Weights are
// wave-uniform (channel loop index uniform) -> scalar loads. LDS reduce.
// ---------------------------------------------------------------------------
__global__ __launch_bounds__(256) void offset_conv_kernel(
    const float* __restrict__ x, const float* __restrict__ ow,
    const float* __restrict__ ob, float* __restrict__ offset) {
  __shared__ float sm_part[4][18][64];
  const int tid  = threadIdx.x;
  const int lane = tid & 63;      // pixel (wo)
  const int wv   = tid >> 6;      // channel group 0..3
  const int blk  = blockIdx.x;    // b*64 + ho
  const int ho   = blk & 63;
  const int b    = blk >> 6;

  const int cbase = __builtin_amdgcn_readfirstlane(wv * 64);
  const float* xb = x + ((size_t)b * CIN + cbase) * HW;

  float acc[18];
  #pragma unroll
  for (int i = 0; i < 18; ++i) acc[i] = 0.0f;

  for (int c = 0; c < 64; ++c) {
    const float* xp = xb + (size_t)c * HW;
    float tap[9];
    #pragma unroll
    for (int ky = 0; ky < 3; ++ky) {
      int y = ho - 1 + ky;
      bool yv = (y >= 0 && y < Hh);
      const float* xr = xp + y * Ww;
      #pragma unroll
      for (int kx = 0; kx < 3; ++kx) {
        int xc = lane - 1 + kx;
        bool v = yv && (xc >= 0) && (xc < Ww);
        tap[ky * 3 + kx] = v ? xr[xc] : 0.0f;
      }
    }
    const float* wp0 = ow + (size_t)(cbase + c) * 9;  // + oc*KDIM per oc
    #pragma unroll
    for (int oc = 0; oc < 18; ++oc) {
      const float* wq = wp0 + (size_t)oc * KDIM;      // wave-uniform -> s_load
      float a = acc[oc];
      #pragma unroll
      for (int k = 0; k < 9; ++k) a = fmaf(tap[k], wq[k], a);
      acc[oc] = a;
    }
  }

  #pragma unroll
  for (int i = 0; i < 18; ++i) sm_part[wv][i][lane] = acc[i];
  __syncthreads();
  for (int i = tid; i < 18 * 64; i += 256) {
    int pp = i & 63;
    int oc = i >> 6;
    float v = sm_part[0][oc][pp] + sm_part[1][oc][pp] +
              sm_part[2][oc][pp] + sm_part[3][oc][pp] + ob[oc];
    offset[((size_t)b * 18 + oc) * HW + (size_t)ho * Ww + pp] = v;
  }
}

// ---------------------------------------------------------------------------
// Kernel 2: transpose weight (COUT, CIN*9) -> wT (CIN*9, COUT)
// ---------------------------------------------------------------------------
__global__ __launch_bounds__(256) void transpose_w_kernel(
    const float* __restrict__ w, float* __restrict__ wT) {
  int idx = blockIdx.x * 256 + threadIdx.x;  // k*256 + oc
  int oc = idx & 255;
  int k  = idx >> 8;
  wT[idx] = w[(size_t)oc * KDIM + k];
}

// ---------------------------------------------------------------------------
// Kernel 3: fused bilinear sampling + implicit GEMM, register-blocked.
// Block = 32 pixels x 256 oc, 256 threads. Grid = 4*64*2 = 512 (2 blocks/CU).
// Thread: pq = tid&7 -> pixels 4pq..4pq+3 ; g = tid>>3 -> oc 8g..8g+7.
// acc = float4 accA[4], accB[4] (32 VGPR, static indexing only).
// Per K-step: 1 ds_read_b128 (samp) + 2 global float4 (weights, L2-resident)
// + 32 v_fmac_f32.
// ---------------------------------------------------------------------------
__global__ __launch_bounds__(256) void deform_main_kernel(
    const float* __restrict__ x, const float* __restrict__ offset,
    const float* __restrict__ wT, float* __restrict__ out) {
  __shared__ int4   sm_idx[9][MT];       // clamped gather indices
  __shared__ float4 sm_w[9][MT];         // mask-folded bilinear weights
  __shared__ float  sm_samp[KSTEPS][MT]; // staged samples for one chunk

  const int tid  = threadIdx.x;
  const int blk  = blockIdx.x;           // ((b*64 + ho)<<1) | half
  const int half = blk & 1;
  const int ho   = (blk >> 1) & 63;
  const int b    = blk >> 7;
  const int p0   = half * MT;

  // ---- Phase 0: bilinear metadata for 9 x 32 (kk, pixel) pairs ----
  const float* offb = offset + (size_t)b * 18 * HW + (size_t)ho * Ww + p0;
  for (int i = tid; i < 9 * MT; i += 256) {
    int pp = i & (MT - 1);
    int kk = i >> 5;                     // 0..8
    int ky = kk / 3, kx = kk % 3;
    float dy = offb[(size_t)(2 * kk) * HW + pp];
    float dx = offb[(size_t)(2 * kk + 1) * HW + pp];
    float py = (float)(ho - 1 + ky) + dy;
    float px = (float)(p0 + pp - 1 + kx) + dx;
    float y0f = floorf(py), x0f = floorf(px);
    int y0 = (int)y0f, x0 = (int)x0f;
    float wy1 = py - y0f, wy0 = 1.0f - wy1;
    float wx1 = px - x0f, wx0 = 1.0f - wx1;
    int4 idx4; float4 w4;
    {
      bool v = (y0 >= 0 && y0 < Hh && x0 >= 0 && x0 < Ww);
      idx4.x = min(max(y0, 0), Hh - 1) * Ww + min(max(x0, 0), Ww - 1);
      w4.x = v ? (wy0 * wx0) : 0.0f;
    }
    {
      int xx = x0 + 1;
      bool v = (y0 >= 0 && y0 < Hh && xx >= 0 && xx < Ww);
      idx4.y = min(max(y0, 0), Hh - 1) * Ww + min(max(xx, 0), Ww - 1);
      w4.y = v ? (wy0 * wx1) : 0.0f;
    }
    {
      int yy = y0 + 1;
      bool v = (yy >= 0 && yy < Hh && x0 >= 0 && x0 < Ww);
      idx4.z = min(max(yy, 0), Hh - 1) * Ww + min(max(x0, 0), Ww - 1);
      w4.z = v ? (wy1 * wx0) : 0.0f;
    }
    {
      int yy = y0 + 1, xx = x0 + 1;
      bool v = (yy >= 0 && yy < Hh && xx >= 0 && xx < Ww);
      idx4.w = min(max(yy, 0), Hh - 1) * Ww + min(max(xx, 0), Ww - 1);
      w4.w = v ? (wy1 * wx1) : 0.0f;
    }
    sm_idx[kk][pp] = idx4;
    sm_w[kk][pp]   = w4;
  }

  float4 accA[4], accB[4];
  #pragma unroll
  for (int i = 0; i < 4; ++i) {
    accA[i] = make_float4(0.f, 0.f, 0.f, 0.f);
    accB[i] = make_float4(0.f, 0.f, 0.f, 0.f);
  }

  const float* xb = x + (size_t)b * CIN * HW;
  const int pq = tid & 7;
  const int g  = tid >> 3;

  for (int c0 = 0; c0 < CIN; c0 += CCHUNK) {
    __syncthreads();   // prev FMA phase done reading sm_samp (also covers meta)
    // ---- stage samples: 72 K-steps x 32 pixels, 9 per thread ----
    #pragma unroll 3
    for (int it = 0; it < 9; ++it) {
      int i = tid + it * 256;
      int pp = i & (MT - 1);
      int t  = i >> 5;                   // cl*9 + kk
      int kk = t % 9;
      int cl = t / 9;
      const float* xp = xb + (size_t)(c0 + cl) * HW;
      int4   ip = sm_idx[kk][pp];
      float4 wp = sm_w[kk][pp];
      sm_samp[t][pp] = xp[ip.x] * wp.x + xp[ip.y] * wp.y +
                       xp[ip.z] * wp.z + xp[ip.w] * wp.w;
    }
    __syncthreads();
    // ---- FMA phase: 72 K-steps, 4 px x 8 oc per thread ----
    const float* wbase = wT + (size_t)c0 * 9 * COUT + g * 8;
    #pragma unroll 4
    for (int t = 0; t < KSTEPS; ++t) {
      float4 s4 = *(const float4*)&sm_samp[t][pq * 4];
      const float4* wp = (const float4*)(wbase + (size_t)t * COUT);
      float4 wA = wp[0], wB = wp[1];
      #pragma unroll
      for (int px = 0; px < 4; ++px) {
        float sv = (px == 0) ? s4.x : (px == 1) ? s4.y : (px == 2) ? s4.z : s4.w;
        accA[px].x = fmaf(sv, wA.x, accA[px].x);
        accA[px].y = fmaf(sv, wA.y, accA[px].y);
        accA[px].z = fmaf(sv, wA.z, accA[px].z);
        accA[px].w = fmaf(sv, wA.w, accA[px].w);
        accB[px].x = fmaf(sv, wB.x, accB[px].x);
        accB[px].y = fmaf(sv, wB.y, accB[px].y);
        accB[px].z = fmaf(sv, wB.z, accB[px].z);
        accB[px].w = fmaf(sv, wB.w, accB[px].w);
      }
    }
  }

  // ---- epilogue: out[b][8g+j][ho][p0 + 4pq + px], float4 per oc ----
  float* obp = out + ((size_t)b * COUT + (size_t)g * 8) * HW +
               (size_t)ho * Ww + p0 + pq * 4;
  *(float4*)(obp + 0 * HW) = make_float4(accA[0].x, accA[1].x, accA[2].x, accA[3].x);
  *(float4*)(obp + 1 * HW) = make_float4(accA[0].y, accA[1].y, accA[2].y, accA[3].y);
  *(float4*)(obp + 2 * HW) = make_float4(accA[0].z, accA[1].z, accA[2].z, accA[3].z);
  *(float4*)(obp + 3 * HW) = make_float4(accA[0].w, accA[1].w, accA[2].w, accA[3].w);
  *(float4*)(obp + 4 * HW) = make_float4(accB[0].x, accB[1].x, accB[2].x, accB[3].x);
  *(float4*)(obp + 5 * HW) = make_float4(accB[0].y, accB[1].y, accB[2].y, accB[3].y);
  *(float4*)(obp + 6 * HW) = make_float4(accB[0].z, accB[1].z, accB[2].z, accB[3].z);
  *(float4*)(obp + 7 * HW) = make_float4(accB[0].w, accB[1].w, accB[2].w, accB[3].w);
}

// ---------------------------------------------------------------------------
extern "C" void kernel_launch(void* const* d_in, const int* in_sizes, int n_in,
                              void* d_out, int out_size, void* d_ws, size_t ws_size,
                              hipStream_t stream) {
  const float* x  = (const float*)d_in[0];   // (4,256,64,64)
  const float* ow = (const float*)d_in[1];   // (18,256,3,3)
  const float* ob = (const float*)d_in[2];   // (18,)
  const float* w  = (const float*)d_in[3];   // (256,256,3,3)
  float* out = (float*)d_out;                // (4,256,64,64)

  float* offset = (float*)d_ws;              // 4*18*4096 floats
  float* wT     = offset + (size_t)Bb * 18 * HW;  // 2304*256 floats

  hipLaunchKernelGGL(offset_conv_kernel, dim3(Bb * Hh), dim3(256),
                     0, stream, x, ow, ob, offset);
  hipLaunchKernelGGL(transpose_w_kernel, dim3((KDIM * COUT) / 256), dim3(256),
                     0, stream, w, wT);
  hipLaunchKernelGGL(deform_main_kernel, dim3(Bb * Hh * 2), dim3(256),
                     0, stream, x, offset, wT, out);
}

// Round 4
// 285.227 us; speedup vs baseline: 3.5402x; 1.8448x over previous
//
#include <hip/hip_runtime.h>

#define CIN 256
#define COUT 256
#define Hh 64
#define Ww 64
#define Bb 4
#define HW 4096
#define NKK 9

typedef __attribute__((ext_vector_type(8))) short bf16x8;
typedef __attribute__((ext_vector_type(4))) float f32x4;

__device__ __forceinline__ unsigned short f2bf(float f) {
  unsigned int u = __builtin_bit_cast(unsigned int, f);
  unsigned int r = u + 0x7FFFu + ((u >> 16) & 1u);
  return (unsigned short)(r >> 16);
}
__device__ __forceinline__ float bf2f(unsigned short h) {
  unsigned int u = ((unsigned int)h) << 16;
  return __builtin_bit_cast(float, u);
}

#define WB_ELEMS 589824    // 9*4*16*2*64*8  (main weights, fragment order)
#define WOB_ELEMS 147456   // 9*4*2*2*64*8   (offset-conv weights, oc padded to 32)

// ---------------------------------------------------------------------------
// Prep: pack weights into exact MFMA B-fragment order (bf16).
// wB index [kk][cb][nt][ks][lane][e]: k = kk*256 + cb*64 + ks*32 + (lane>>4)*8 + e
//                                     oc = nt*16 + (lane&15)
// Main weights: hi+lo split. Offset-conv weights: hi only, oc>=18 -> 0.
// ---------------------------------------------------------------------------
__global__ __launch_bounds__(256) void prep_weights_kernel(
    const float* __restrict__ w,   // (256,256,3,3)
    const float* __restrict__ ow,  // (18,256,3,3)
    unsigned short* __restrict__ wBh, unsigned short* __restrict__ wBl,
    unsigned short* __restrict__ wOBh) {
  int i = blockIdx.x * 256 + threadIdx.x;
  if (i < WB_ELEMS) {
    int e = i & 7;
    int lane = (i >> 3) & 63;
    int ks = (i >> 9) & 1;
    int nt = (i >> 10) & 15;
    int cb = (i >> 14) & 3;
    int kk = i >> 16;
    int c = cb * 64 + ks * 32 + (lane >> 4) * 8 + e;
    int oc = nt * 16 + (lane & 15);
    float v = w[((size_t)oc * CIN + c) * 9 + kk];
    unsigned short hi = f2bf(v);
    wBh[i] = hi;
    wBl[i] = f2bf(v - bf2f(hi));
  } else {
    int j = i - WB_ELEMS;
    if (j < WOB_ELEMS) {
      int e = j & 7;
      int lane = (j >> 3) & 63;
      int ks = (j >> 9) & 1;
      int nt = (j >> 10) & 1;
      int cb = (j >> 11) & 3;
      int kk = j >> 13;
      int c = cb * 64 + ks * 32 + (lane >> 4) * 8 + e;
      int oc = nt * 16 + (lane & 15);
      float v = (oc < 18) ? ow[((size_t)oc * CIN + c) * 9 + kk] : 0.0f;
      wOBh[j] = f2bf(v);
    }
  }
}

// ---------------------------------------------------------------------------
// Offset conv via MFMA (single bf16 — offsets tolerate ~1e-3 jitter).
// Block = (b,ho): 64 px, 256 threads = 4 waves; wave = px m-tile.
// Chunk = (kk, 64 channels): stage shifted x into swizzled LDS (bf16),
// 4 MFMAs/wave/chunk against wOBh (N padded to 32, valid oc<18).
// ---------------------------------------------------------------------------
__global__ __launch_bounds__(256) void offset_conv_kernel(
    const float* __restrict__ x,
    const unsigned short* __restrict__ wOBh,
    const float* __restrict__ ob,
    float* __restrict__ offset) {
  __shared__ __align__(16) unsigned short smA[64 * 64];  // [px][c] bf16, swizzled

  const int tid = threadIdx.x;
  const int blk = blockIdx.x;   // b*64 + ho
  const int ho = blk & 63;
  const int b  = blk >> 6;
  const int lane = tid & 63;
  const int wv = tid >> 6;      // m-tile
  const int px = tid & 63;
  const int c8g = tid >> 6;

  f32x4 acc[2];
  #pragma unroll
  for (int n = 0; n < 2; ++n)
    #pragma unroll
    for (int q = 0; q < 4; ++q) acc[n][q] = 0.0f;

  const float* xb = x + (size_t)b * CIN * HW;

  for (int kk = 0; kk < NKK; ++kk) {
    int ky = kk / 3, kx = kk % 3;
    int y = ho - 1 + ky;
    if (y < 0 || y >= Hh) continue;          // block-uniform: A all-zero
    int xx = px - 1 + kx;
    bool xv = (xx >= 0 && xx < Ww);
    int xxc = min(max(xx, 0), Ww - 1);
    const float* xrow = xb + (size_t)y * Ww + xxc;
    for (int cb = 0; cb < 4; ++cb) {
      __syncthreads();
      #pragma unroll
      for (int pass = 0; pass < 2; ++pass) {
        int c8 = c8g * 2 + pass;             // 0..7
        int cbase = cb * 64 + c8 * 8;
        unsigned int ph[4];
        #pragma unroll
        for (int j = 0; j < 4; ++j) {
          float v0 = xv ? xrow[(size_t)(cbase + 2 * j) * HW] : 0.0f;
          float v1 = xv ? xrow[(size_t)(cbase + 2 * j + 1) * HW] : 0.0f;
          ph[j] = (unsigned int)f2bf(v0) | ((unsigned int)f2bf(v1) << 16);
        }
        int boff = px * 128 + ((c8 ^ (px & 7)) * 16);
        *(uint4*)((char*)smA + boff) = make_uint4(ph[0], ph[1], ph[2], ph[3]);
      }
      __syncthreads();
      bf16x8 a[2];
      #pragma unroll
      for (int ks = 0; ks < 2; ++ks) {
        int pxa = wv * 16 + (lane & 15);
        int cg = ks * 4 + (lane >> 4);
        a[ks] = *(const bf16x8*)((const char*)smA + pxa * 128 + ((cg ^ (pxa & 7)) * 16));
      }
      #pragma unroll
      for (int nt = 0; nt < 2; ++nt) {
        #pragma unroll
        for (int ks = 0; ks < 2; ++ks) {
          size_t wi = ((((size_t)(kk * 4 + cb) * 2 + nt) * 2 + ks) * 64 + lane) * 8;
          bf16x8 bh = *(const bf16x8*)(wOBh + wi);
          acc[nt] = __builtin_amdgcn_mfma_f32_16x16x32_bf16(a[ks], bh, acc[nt], 0, 0, 0);
        }
      }
    }
  }
  // epilogue: D row=(lane>>4)*4+reg (px), col=lane&15 (oc)
  #pragma unroll
  for (int nt = 0; nt < 2; ++nt) {
    int oc = nt * 16 + (lane & 15);
    if (oc < 18) {
      float bias = ob[oc];
      float4 v4 = make_float4(acc[nt][0] + bias, acc[nt][1] + bias,
                              acc[nt][2] + bias, acc[nt][3] + bias);
      int pxo = wv * 16 + (lane >> 4) * 4;
      *(float4*)(offset + ((size_t)b * 18 + oc) * HW + (size_t)ho * Ww + pxo) = v4;
    }
  }
}

// ---------------------------------------------------------------------------
// Main: fused bilinear sample + MFMA GEMM, 3-term bf16 split (~fp32 accuracy).
// Block = (b,ho): 64 px x 256 oc, 512 threads = 8 waves.
// Wave wv: mh=wv>>2 -> px half (32 px), og=wv&3 -> oc group (64 oc).
// Chunk = (kk, 64 c). Double-buffered swizzled LDS A (hi+lo); gathers for
// chunk t+1 issued before chunk t's MFMAs (latency hidden), converted+written
// after. 48 MFMAs/wave/chunk.
// ---------------------------------------------------------------------------
__global__ __launch_bounds__(512) void deform_main_kernel(
    const float* __restrict__ x, const float* __restrict__ offset,
    const unsigned short* __restrict__ wBh, const unsigned short* __restrict__ wBl,
    float* __restrict__ out) {
  __shared__ __align__(16) int4   sm_idx[NKK][64];
  __shared__ __align__(16) float4 sm_w[NKK][64];
  __shared__ __align__(16) unsigned short smAh[2][64 * 64];
  __shared__ __align__(16) unsigned short smAl[2][64 * 64];

  const int tid = threadIdx.x;
  const int blk = blockIdx.x;   // b*64 + ho
  const int ho = blk & 63;
  const int b  = blk >> 6;
  const int lane = tid & 63;
  const int wv = tid >> 6;
  const int mh = wv >> 2;       // px half
  const int og = wv & 3;        // oc group

  // ---- Phase 0: bilinear meta for 9 x 64 (kk, px) ----
  const float* offb = offset + (size_t)b * 18 * HW + (size_t)ho * Ww;
  for (int i = tid; i < NKK * 64; i += 512) {
    int pp = i & 63;
    int kk = i >> 6;
    int ky = kk / 3, kx = kk % 3;
    float dy = offb[(size_t)(2 * kk) * HW + pp];
    float dx = offb[(size_t)(2 * kk + 1) * HW + pp];
    float py = (float)(ho - 1 + ky) + dy;
    float pxf = (float)(pp - 1 + kx) + dx;
    float y0f = floorf(py), x0f = floorf(pxf);
    int y0 = (int)y0f, x0 = (int)x0f;
    float wy1 = py - y0f, wy0 = 1.0f - wy1;
    float wx1 = pxf - x0f, wx0 = 1.0f - wx1;
    int4 idx4; float4 w4;
    { bool v = (y0 >= 0 && y0 < Hh && x0 >= 0 && x0 < Ww);
      idx4.x = min(max(y0, 0), Hh - 1) * Ww + min(max(x0, 0), Ww - 1);
      w4.x = v ? wy0 * wx0 : 0.0f; }
    { int xs = x0 + 1; bool v = (y0 >= 0 && y0 < Hh && xs >= 0 && xs < Ww);
      idx4.y = min(max(y0, 0), Hh - 1) * Ww + min(max(xs, 0), Ww - 1);
      w4.y = v ? wy0 * wx1 : 0.0f; }
    { int ys = y0 + 1; bool v = (ys >= 0 && ys < Hh && x0 >= 0 && x0 < Ww);
      idx4.z = min(max(ys, 0), Hh - 1) * Ww + min(max(x0, 0), Ww - 1);
      w4.z = v ? wy1 * wx0 : 0.0f; }
    { int ys = y0 + 1, xs = x0 + 1; bool v = (ys >= 0 && ys < Hh && xs >= 0 && xs < Ww);
      idx4.w = min(max(ys, 0), Hh - 1) * Ww + min(max(xs, 0), Ww - 1);
      w4.w = v ? wy1 * wx1 : 0.0f; }
    sm_idx[kk][pp] = idx4;
    sm_w[kk][pp] = w4;
  }
  __syncthreads();

  f32x4 acc[2][4];
  #pragma unroll
  for (int m = 0; m < 2; ++m)
    #pragma unroll
    for (int n = 0; n < 4; ++n)
      #pragma unroll
      for (int q = 0; q < 4; ++q) acc[m][n][q] = 0.0f;

  const float* xb = x + (size_t)b * CIN * HW;
  const int spx = tid & 63;   // stage pixel
  const int sc8 = tid >> 6;   // stage 8-channel group (0..7)
  const int sboff = spx * 128 + ((sc8 ^ (spx & 7)) * 16);

  // ---- prologue: stage chunk 0 (kk=0, cb=0) ----
  {
    int4 ip = sm_idx[0][spx];
    float4 wp = sm_w[0][spx];
    const float* xpB = xb + (size_t)(sc8 * 8) * HW;
    unsigned int ph[4], pl[4];
    #pragma unroll
    for (int j2 = 0; j2 < 4; ++j2) {
      const float* xp0 = xpB + (size_t)(2 * j2) * HW;
      const float* xp1 = xpB + (size_t)(2 * j2 + 1) * HW;
      float v0 = xp0[ip.x] * wp.x + xp0[ip.y] * wp.y + xp0[ip.z] * wp.z + xp0[ip.w] * wp.w;
      float v1 = xp1[ip.x] * wp.x + xp1[ip.y] * wp.y + xp1[ip.z] * wp.z + xp1[ip.w] * wp.w;
      unsigned short h0 = f2bf(v0), h1 = f2bf(v1);
      ph[j2] = (unsigned int)h0 | ((unsigned int)h1 << 16);
      pl[j2] = (unsigned int)f2bf(v0 - bf2f(h0)) | ((unsigned int)f2bf(v1 - bf2f(h1)) << 16);
    }
    *(uint4*)((char*)smAh[0] + sboff) = make_uint4(ph[0], ph[1], ph[2], ph[3]);
    *(uint4*)((char*)smAl[0] + sboff) = make_uint4(pl[0], pl[1], pl[2], pl[3]);
  }
  __syncthreads();

  for (int ch = 0; ch < 36; ++ch) {
    const int cur = ch & 1;
    // ---- issue gathers for chunk ch+1 (results land after MFMAs) ----
    float gg[8][4];
    int4 ipn; float4 wpn;
    const bool have_next = (ch + 1 < 36);
    if (have_next) {
      int kkn = (ch + 1) >> 2, cbn = (ch + 1) & 3;
      ipn = sm_idx[kkn][spx];
      wpn = sm_w[kkn][spx];
      const float* xpB = xb + (size_t)(cbn * 64 + sc8 * 8) * HW;
      #pragma unroll
      for (int j = 0; j < 8; ++j) {
        const float* xp = xpB + (size_t)j * HW;
        gg[j][0] = xp[ipn.x];
        gg[j][1] = xp[ipn.y];
        gg[j][2] = xp[ipn.z];
        gg[j][3] = xp[ipn.w];
      }
    }
    // ---- MFMAs for chunk ch from buffer cur ----
    {
      int kk = ch >> 2, cb = ch & 3;
      bf16x8 ah[2][2], al[2][2];
      #pragma unroll
      for (int m = 0; m < 2; ++m)
        #pragma unroll
        for (int ks = 0; ks < 2; ++ks) {
          int pxa = mh * 32 + m * 16 + (lane & 15);
          int cg = ks * 4 + (lane >> 4);
          int aoff = pxa * 128 + ((cg ^ (pxa & 7)) * 16);
          ah[m][ks] = *(const bf16x8*)((const char*)smAh[cur] + aoff);
          al[m][ks] = *(const bf16x8*)((const char*)smAl[cur] + aoff);
        }
      #pragma unroll
      for (int nt = 0; nt < 4; ++nt) {
        #pragma unroll
        for (int ks = 0; ks < 2; ++ks) {
          size_t wi = ((((size_t)(kk * 4 + cb) * 16 + (og * 4 + nt)) * 2 + ks) * 64 + lane) * 8;
          bf16x8 bh = *(const bf16x8*)(wBh + wi);
          bf16x8 bl = *(const bf16x8*)(wBl + wi);
          acc[0][nt] = __builtin_amdgcn_mfma_f32_16x16x32_bf16(ah[0][ks], bh, acc[0][nt], 0, 0, 0);
          acc[1][nt] = __builtin_amdgcn_mfma_f32_16x16x32_bf16(ah[1][ks], bh, acc[1][nt], 0, 0, 0);
          acc[0][nt] = __builtin_amdgcn_mfma_f32_16x16x32_bf16(al[0][ks], bh, acc[0][nt], 0, 0, 0);
          acc[1][nt] = __builtin_amdgcn_mfma_f32_16x16x32_bf16(al[1][ks], bh, acc[1][nt], 0, 0, 0);
          acc[0][nt] = __builtin_amdgcn_mfma_f32_16x16x32_bf16(ah[0][ks], bl, acc[0][nt], 0, 0, 0);
          acc[1][nt] = __builtin_amdgcn_mfma_f32_16x16x32_bf16(ah[1][ks], bl, acc[1][nt], 0, 0, 0);
        }
      }
    }
    // ---- finish stage for chunk ch+1 into buffer cur^1 ----
    if (have_next) {
      unsigned int ph[4], pl[4];
      #pragma unroll
      for (int j2 = 0; j2 < 4; ++j2) {
        float v0 = gg[2 * j2][0] * wpn.x + gg[2 * j2][1] * wpn.y +
                   gg[2 * j2][2] * wpn.z + gg[2 * j2][3] * wpn.w;
        float v1 = gg[2 * j2 + 1][0] * wpn.x + gg[2 * j2 + 1][1] * wpn.y +
                   gg[2 * j2 + 1][2] * wpn.z + gg[2 * j2 + 1][3] * wpn.w;
        unsigned short h0 = f2bf(v0), h1 = f2bf(v1);
        ph[j2] = (unsigned int)h0 | ((unsigned int)h1 << 16);
        pl[j2] = (unsigned int)f2bf(v0 - bf2f(h0)) | ((unsigned int)f2bf(v1 - bf2f(h1)) << 16);
      }
      *(uint4*)((char*)smAh[cur ^ 1] + sboff) = make_uint4(ph[0], ph[1], ph[2], ph[3]);
      *(uint4*)((char*)smAl[cur ^ 1] + sboff) = make_uint4(pl[0], pl[1], pl[2], pl[3]);
    }
    __syncthreads();
  }

  // ---- epilogue: px = mh*32 + m*16 + (lane>>4)*4 + r (4 consecutive -> float4) ----
  #pragma unroll
  for (int m = 0; m < 2; ++m) {
    #pragma unroll
    for (int nt = 0; nt < 4; ++nt) {
      int oc = og * 64 + nt * 16 + (lane & 15);
      int pxo = mh * 32 + m * 16 + (lane >> 4) * 4;
      float4 v4 = make_float4(acc[m][nt][0], acc[m][nt][1], acc[m][nt][2], acc[m][nt][3]);
      *(float4*)(out + ((size_t)b * COUT + oc) * HW + (size_t)ho * Ww + pxo) = v4;
    }
  }
}

// ---------------------------------------------------------------------------
extern "C" void kernel_launch(void* const* d_in, const int* in_sizes, int n_in,
                              void* d_out, int out_size, void* d_ws, size_t ws_size,
                              hipStream_t stream) {
  const float* x  = (const float*)d_in[0];   // (4,256,64,64)
  const float* ow = (const float*)d_in[1];   // (18,256,3,3)
  const float* ob = (const float*)d_in[2];   // (18,)
  const float* w  = (const float*)d_in[3];   // (256,256,3,3)
  float* out = (float*)d_out;                // (4,256,64,64)

  // ws layout (bytes): offset fp32 [0,1179648) | wBh | wBl | wOBh  = 3.83 MB
  float* offset = (float*)d_ws;
  unsigned short* wBh  = (unsigned short*)((char*)d_ws + 1179648);
  unsigned short* wBl  = wBh + WB_ELEMS;
  unsigned short* wOBh = wBl + WB_ELEMS;

  hipLaunchKernelGGL(prep_weights_kernel, dim3((WB_ELEMS + WOB_ELEMS) / 256),
                     dim3(256), 0, stream, w, ow, wBh, wBl, wOBh);
  hipLaunchKernelGGL(offset_conv_kernel, dim3(Bb * Hh), dim3(256),
                     0, stream, x, wOBh, ob, offset);
  hipLaunchKernelGGL(deform_main_kernel, dim3(Bb * Hh), dim3(512),
                     0, stream, x, offset, wBh, wBl, out);
}

// Round 5
// 268.723 us; speedup vs baseline: 3.7576x; 1.0614x over previous
//
#include <hip/hip_runtime.h>

#define CIN 256
#define COUT 256
#define Hh 64
#define Ww 64
#define Bb 4
#define HW 4096
#define NKK 9

typedef __attribute__((ext_vector_type(8))) short bf16x8;
typedef __attribute__((ext_vector_type(4))) float f32x4;

__device__ __forceinline__ unsigned short f2bf(float f) {
  unsigned int u = __builtin_bit_cast(unsigned int, f);
  unsigned int r = u + 0x7FFFu + ((u >> 16) & 1u);
  return (unsigned short)(r >> 16);
}
__device__ __forceinline__ float bf2f(unsigned short h) {
  unsigned int u = ((unsigned int)h) << 16;
  return __builtin_bit_cast(float, u);
}

#define WB_ELEMS 589824    // 9*4*16*2*64*8  (main weights, fragment order)
#define WOB_ELEMS 147456   // 9*4*2*2*64*8   (offset-conv weights, oc padded to 32)

// ---------------------------------------------------------------------------
// Prep: pack weights into exact MFMA B-fragment order (bf16).
// wB index [kk][cb][nt][ks][lane][e]: k = kk*256 + cb*64 + ks*32 + (lane>>4)*8 + e
//                                     oc = nt*16 + (lane&15)
// Main weights: hi+lo split. Offset-conv weights: hi only, oc>=18 -> 0.
// ---------------------------------------------------------------------------
__global__ __launch_bounds__(256) void prep_weights_kernel(
    const float* __restrict__ w,   // (256,256,3,3)
    const float* __restrict__ ow,  // (18,256,3,3)
    unsigned short* __restrict__ wBh, unsigned short* __restrict__ wBl,
    unsigned short* __restrict__ wOBh) {
  int i = blockIdx.x * 256 + threadIdx.x;
  if (i < WB_ELEMS) {
    int e = i & 7;
    int lane = (i >> 3) & 63;
    int ks = (i >> 9) & 1;
    int nt = (i >> 10) & 15;
    int cb = (i >> 14) & 3;
    int kk = i >> 16;
    int c = cb * 64 + ks * 32 + (lane >> 4) * 8 + e;
    int oc = nt * 16 + (lane & 15);
    float v = w[((size_t)oc * CIN + c) * 9 + kk];
    unsigned short hi = f2bf(v);
    wBh[i] = hi;
    wBl[i] = f2bf(v - bf2f(hi));
  } else {
    int j = i - WB_ELEMS;
    if (j < WOB_ELEMS) {
      int e = j & 7;
      int lane = (j >> 3) & 63;
      int ks = (j >> 9) & 1;
      int nt = (j >> 10) & 1;
      int cb = (j >> 11) & 3;
      int kk = j >> 13;
      int c = cb * 64 + ks * 32 + (lane >> 4) * 8 + e;
      int oc = nt * 16 + (lane & 15);
      float v = (oc < 18) ? ow[((size_t)oc * CIN + c) * 9 + kk] : 0.0f;
      wOBh[j] = f2bf(v);
    }
  }
}

// ---------------------------------------------------------------------------
// Offset conv via MFMA (single bf16 — offsets tolerate ~1e-3 jitter).
// Block = (b,ho): 64 px, 256 threads = 4 waves; wave = px m-tile.
// XCD-swizzled blockIdx (T1): XCD k owns a contiguous half-image of one batch.
// ---------------------------------------------------------------------------
__global__ __launch_bounds__(256) void offset_conv_kernel(
    const float* __restrict__ x,
    const unsigned short* __restrict__ wOBh,
    const float* __restrict__ ob,
    float* __restrict__ offset) {
  __shared__ __align__(16) unsigned short smA[64 * 64];  // [px][c] bf16, swizzled

  const int tid = threadIdx.x;
  const int bid = blockIdx.x;
  const int blk = (bid & 7) * 32 + (bid >> 3);  // T1: XCD-contiguous logical id
  const int ho = blk & 63;
  const int b  = blk >> 6;
  const int lane = tid & 63;
  const int wv = tid >> 6;      // m-tile
  const int px = tid & 63;
  const int c8g = tid >> 6;

  f32x4 acc[2];
  #pragma unroll
  for (int n = 0; n < 2; ++n)
    #pragma unroll
    for (int q = 0; q < 4; ++q) acc[n][q] = 0.0f;

  const float* xb = x + (size_t)b * CIN * HW;

  for (int kk = 0; kk < NKK; ++kk) {
    int ky = kk / 3, kx = kk % 3;
    int y = ho - 1 + ky;
    if (y < 0 || y >= Hh) continue;          // block-uniform: A all-zero
    int xx = px - 1 + kx;
    bool xv = (xx >= 0 && xx < Ww);
    int xxc = min(max(xx, 0), Ww - 1);
    const float* xrow = xb + (size_t)y * Ww + xxc;
    for (int cb = 0; cb < 4; ++cb) {
      __syncthreads();
      #pragma unroll
      for (int pass = 0; pass < 2; ++pass) {
        int c8 = c8g * 2 + pass;             // 0..7
        int cbase = cb * 64 + c8 * 8;
        unsigned int ph[4];
        #pragma unroll
        for (int j = 0; j < 4; ++j) {
          float v0 = xv ? xrow[(size_t)(cbase + 2 * j) * HW] : 0.0f;
          float v1 = xv ? xrow[(size_t)(cbase + 2 * j + 1) * HW] : 0.0f;
          ph[j] = (unsigned int)f2bf(v0) | ((unsigned int)f2bf(v1) << 16);
        }
        int boff = px * 128 + ((c8 ^ (px & 7)) * 16);
        *(uint4*)((char*)smA + boff) = make_uint4(ph[0], ph[1], ph[2], ph[3]);
      }
      __syncthreads();
      bf16x8 a[2];
      #pragma unroll
      for (int ks = 0; ks < 2; ++ks) {
        int pxa = wv * 16 + (lane & 15);
        int cg = ks * 4 + (lane >> 4);
        a[ks] = *(const bf16x8*)((const char*)smA + pxa * 128 + ((cg ^ (pxa & 7)) * 16));
      }
      #pragma unroll
      for (int nt = 0; nt < 2; ++nt) {
        #pragma unroll
        for (int ks = 0; ks < 2; ++ks) {
          size_t wi = ((((size_t)(kk * 4 + cb) * 2 + nt) * 2 + ks) * 64 + lane) * 8;
          bf16x8 bh = *(const bf16x8*)(wOBh + wi);
          acc[nt] = __builtin_amdgcn_mfma_f32_16x16x32_bf16(a[ks], bh, acc[nt], 0, 0, 0);
        }
      }
    }
  }
  // epilogue: D row=(lane>>4)*4+reg (px), col=lane&15 (oc)
  #pragma unroll
  for (int nt = 0; nt < 2; ++nt) {
    int oc = nt * 16 + (lane & 15);
    if (oc < 18) {
      float bias = ob[oc];
      float4 v4 = make_float4(acc[nt][0] + bias, acc[nt][1] + bias,
                              acc[nt][2] + bias, acc[nt][3] + bias);
      int pxo = wv * 16 + (lane >> 4) * 4;
      *(float4*)(offset + ((size_t)b * 18 + oc) * HW + (size_t)ho * Ww + pxo) = v4;
    }
  }
}

// ---------------------------------------------------------------------------
// Main: fused bilinear sample + MFMA GEMM, 3-term bf16 split (~fp32 accuracy).
// Block = (b,ho): 64 px x 256 oc, 512 threads = 8 waves.
// XCD-swizzled blockIdx (T1): same mapping as offset_conv, so the 32 blocks
// on one XCD share x rows (~2.2 MB) + the weight stream (2.25 MB) in L2.
// ---------------------------------------------------------------------------
__global__ __launch_bounds__(512) void deform_main_kernel(
    const float* __restrict__ x, const float* __restrict__ offset,
    const unsigned short* __restrict__ wBh, const unsigned short* __restrict__ wBl,
    float* __restrict__ out) {
  __shared__ __align__(16) int4   sm_idx[NKK][64];
  __shared__ __align__(16) float4 sm_w[NKK][64];
  __shared__ __align__(16) unsigned short smAh[2][64 * 64];
  __shared__ __align__(16) unsigned short smAl[2][64 * 64];

  const int tid = threadIdx.x;
  const int bid = blockIdx.x;
  const int blk = (bid & 7) * 32 + (bid >> 3);  // T1: XCD-contiguous logical id
  const int ho = blk & 63;
  const int b  = blk >> 6;
  const int lane = tid & 63;
  const int wv = tid >> 6;
  const int mh = wv >> 2;       // px half
  const int og = wv & 3;        // oc group

  // ---- Phase 0: bilinear meta for 9 x 64 (kk, px) ----
  const float* offb = offset + (size_t)b * 18 * HW + (size_t)ho * Ww;
  for (int i = tid; i < NKK * 64; i += 512) {
    int pp = i & 63;
    int kk = i >> 6;
    int ky = kk / 3, kx = kk % 3;
    float dy = offb[(size_t)(2 * kk) * HW + pp];
    float dx = offb[(size_t)(2 * kk + 1) * HW + pp];
    float py = (float)(ho - 1 + ky) + dy;
    float pxf = (float)(pp - 1 + kx) + dx;
    float y0f = floorf(py), x0f = floorf(pxf);
    int y0 = (int)y0f, x0 = (int)x0f;
    float wy1 = py - y0f, wy0 = 1.0f - wy1;
    float wx1 = pxf - x0f, wx0 = 1.0f - wx1;
    int4 idx4; float4 w4;
    { bool v = (y0 >= 0 && y0 < Hh && x0 >= 0 && x0 < Ww);
      idx4.x = min(max(y0, 0), Hh - 1) * Ww + min(max(x0, 0), Ww - 1);
      w4.x = v ? wy0 * wx0 : 0.0f; }
    { int xs = x0 + 1; bool v = (y0 >= 0 && y0 < Hh && xs >= 0 && xs < Ww);
      idx4.y = min(max(y0, 0), Hh - 1) * Ww + min(max(xs, 0), Ww - 1);
      w4.y = v ? wy0 * wx1 : 0.0f; }
    { int ys = y0 + 1; bool v = (ys >= 0 && ys < Hh && x0 >= 0 && x0 < Ww);
      idx4.z = min(max(ys, 0), Hh - 1) * Ww + min(max(x0, 0), Ww - 1);
      w4.z = v ? wy1 * wx0 : 0.0f; }
    { int ys = y0 + 1, xs = x0 + 1; bool v = (ys >= 0 && ys < Hh && xs >= 0 && xs < Ww);
      idx4.w = min(max(ys, 0), Hh - 1) * Ww + min(max(xs, 0), Ww - 1);
      w4.w = v ? wy1 * wx1 : 0.0f; }
    sm_idx[kk][pp] = idx4;
    sm_w[kk][pp] = w4;
  }
  __syncthreads();

  f32x4 acc[2][4];
  #pragma unroll
  for (int m = 0; m < 2; ++m)
    #pragma unroll
    for (int n = 0; n < 4; ++n)
      #pragma unroll
      for (int q = 0; q < 4; ++q) acc[m][n][q] = 0.0f;

  const float* xb = x + (size_t)b * CIN * HW;
  const int spx = tid & 63;   // stage pixel
  const int sc8 = tid >> 6;   // stage 8-channel group (0..7)
  const int sboff = spx * 128 + ((sc8 ^ (spx & 7)) * 16);

  // ---- prologue: stage chunk 0 (kk=0, cb=0) ----
  {
    int4 ip = sm_idx[0][spx];
    float4 wp = sm_w[0][spx];
    const float* xpB = xb + (size_t)(sc8 * 8) * HW;
    unsigned int ph[4], pl[4];
    #pragma unroll
    for (int j2 = 0; j2 < 4; ++j2) {
      const float* xp0 = xpB + (size_t)(2 * j2) * HW;
      const float* xp1 = xpB + (size_t)(2 * j2 + 1) * HW;
      float v0 = xp0[ip.x] * wp.x + xp0[ip.y] * wp.y + xp0[ip.z] * wp.z + xp0[ip.w] * wp.w;
      float v1 = xp1[ip.x] * wp.x + xp1[ip.y] * wp.y + xp1[ip.z] * wp.z + xp1[ip.w] * wp.w;
      unsigned short h0 = f2bf(v0), h1 = f2bf(v1);
      ph[j2] = (unsigned int)h0 | ((unsigned int)h1 << 16);
      pl[j2] = (unsigned int)f2bf(v0 - bf2f(h0)) | ((unsigned int)f2bf(v1 - bf2f(h1)) << 16);
    }
    *(uint4*)((char*)smAh[0] + sboff) = make_uint4(ph[0], ph[1], ph[2], ph[3]);
    *(uint4*)((char*)smAl[0] + sboff) = make_uint4(pl[0], pl[1], pl[2], pl[3]);
  }
  __syncthreads();

  for (int ch = 0; ch < 36; ++ch) {
    const int cur = ch & 1;
    // ---- issue gathers for chunk ch+1 (results land after MFMAs) ----
    float gg[8][4];
    int4 ipn; float4 wpn;
    const bool have_next = (ch + 1 < 36);
    if (have_next) {
      int kkn = (ch + 1) >> 2, cbn = (ch + 1) & 3;
      ipn = sm_idx[kkn][spx];
      wpn = sm_w[kkn][spx];
      const float* xpB = xb + (size_t)(cbn * 64 + sc8 * 8) * HW;
      #pragma unroll
      for (int j = 0; j < 8; ++j) {
        const float* xp = xpB + (size_t)j * HW;
        gg[j][0] = xp[ipn.x];
        gg[j][1] = xp[ipn.y];
        gg[j][2] = xp[ipn.z];
        gg[j][3] = xp[ipn.w];
      }
    }
    // ---- MFMAs for chunk ch from buffer cur ----
    {
      int kk = ch >> 2, cb = ch & 3;
      bf16x8 ah[2][2], al[2][2];
      #pragma unroll
      for (int m = 0; m < 2; ++m)
        #pragma unroll
        for (int ks = 0; ks < 2; ++ks) {
          int pxa = mh * 32 + m * 16 + (lane & 15);
          int cg = ks * 4 + (lane >> 4);
          int aoff = pxa * 128 + ((cg ^ (pxa & 7)) * 16);
          ah[m][ks] = *(const bf16x8*)((const char*)smAh[cur] + aoff);
          al[m][ks] = *(const bf16x8*)((const char*)smAl[cur] + aoff);
        }
      #pragma unroll
      for (int nt = 0; nt < 4; ++nt) {
        #pragma unroll
        for (int ks = 0; ks < 2; ++ks) {
          size_t wi = ((((size_t)(kk * 4 + cb) * 16 + (og * 4 + nt)) * 2 + ks) * 64 + lane) * 8;
          bf16x8 bh = *(const bf16x8*)(wBh + wi);
          bf16x8 bl = *(const bf16x8*)(wBl + wi);
          acc[0][nt] = __builtin_amdgcn_mfma_f32_16x16x32_bf16(ah[0][ks], bh, acc[0][nt], 0, 0, 0);
          acc[1][nt] = __builtin_amdgcn_mfma_f32_16x16x32_bf16(ah[1][ks], bh, acc[1][nt], 0, 0, 0);
          acc[0][nt] = __builtin_amdgcn_mfma_f32_16x16x32_bf16(al[0][ks], bh, acc[0][nt], 0, 0, 0);
          acc[1][nt] = __builtin_amdgcn_mfma_f32_16x16x32_bf16(al[1][ks], bh, acc[1][nt], 0, 0, 0);
          acc[0][nt] = __builtin_amdgcn_mfma_f32_16x16x32_bf16(ah[0][ks], bl, acc[0][nt], 0, 0, 0);
          acc[1][nt] = __builtin_amdgcn_mfma_f32_16x16x32_bf16(ah[1][ks], bl, acc[1][nt], 0, 0, 0);
        }
      }
    }
    // ---- finish stage for chunk ch+1 into buffer cur^1 ----
    if (have_next) {
      unsigned int ph[4], pl[4];
      #pragma unroll
      for (int j2 = 0; j2 < 4; ++j2) {
        float v0 = gg[2 * j2][0] * wpn.x + gg[2 * j2][1] * wpn.y +
                   gg[2 * j2][2] * wpn.z + gg[2 * j2][3] * wpn.w;
        float v1 = gg[2 * j2 + 1][0] * wpn.x + gg[2 * j2 + 1][1] * wpn.y +
                   gg[2 * j2 + 1][2] * wpn.z + gg[2 * j2 + 1][3] * wpn.w;
        unsigned short h0 = f2bf(v0), h1 = f2bf(v1);
        ph[j2] = (unsigned int)h0 | ((unsigned int)h1 << 16);
        pl[j2] = (unsigned int)f2bf(v0 - bf2f(h0)) | ((unsigned int)f2bf(v1 - bf2f(h1)) << 16);
      }
      *(uint4*)((char*)smAh[cur ^ 1] + sboff) = make_uint4(ph[0], ph[1], ph[2], ph[3]);
      *(uint4*)((char*)smAl[cur ^ 1] + sboff) = make_uint4(pl[0], pl[1], pl[2], pl[3]);
    }
    __syncthreads();
  }

  // ---- epilogue: px = mh*32 + m*16 + (lane>>4)*4 + r (4 consecutive -> float4) ----
  #pragma unroll
  for (int m = 0; m < 2; ++m) {
    #pragma unroll
    for (int nt = 0; nt < 4; ++nt) {
      int oc = og * 64 + nt * 16 + (lane & 15);
      int pxo = mh * 32 + m * 16 + (lane >> 4) * 4;
      float4 v4 = make_float4(acc[m][nt][0], acc[m][nt][1], acc[m][nt][2], acc[m][nt][3]);
      *(float4*)(out + ((size_t)b * COUT + oc) * HW + (size_t)ho * Ww + pxo) = v4;
    }
  }
}

// ---------------------------------------------------------------------------
extern "C" void kernel_launch(void* const* d_in, const int* in_sizes, int n_in,
                              void* d_out, int out_size, void* d_ws, size_t ws_size,
                              hipStream_t stream) {
  const float* x  = (const float*)d_in[0];   // (4,256,64,64)
  const float* ow = (const float*)d_in[1];   // (18,256,3,3)
  const float* ob = (const float*)d_in[2];   // (18,)
  const float* w  = (const float*)d_in[3];   // (256,256,3,3)
  float* out = (float*)d_out;                // (4,256,64,64)

  // ws layout (bytes): offset fp32 [0,1179648) | wBh | wBl | wOBh  = 3.83 MB
  float* offset = (float*)d_ws;
  unsigned short* wBh  = (unsigned short*)((char*)d_ws + 1179648);
  unsigned short* wBl  = wBh + WB_ELEMS;
  unsigned short* wOBh = wBl + WB_ELEMS;

  hipLaunchKernelGGL(prep_weights_kernel, dim3((WB_ELEMS + WOB_ELEMS) / 256),
                     dim3(256), 0, stream, w, ow, wBh, wBl, wOBh);
  hipLaunchKernelGGL(offset_conv_kernel, dim3(Bb * Hh), dim3(256),
                     0, stream, x, wOBh, ob, offset);
  hipLaunchKernelGGL(deform_main_kernel, dim3(Bb * Hh), dim3(512),
                     0, stream, x, offset, wBh, wBl, out);
}

// Round 7
// 265.288 us; speedup vs baseline: 3.8063x; 1.0129x over previous
//
#include <hip/hip_runtime.h>

#define CIN 256
#define COUT 256
#define Hh 64
#define Ww 64
#define Bb 4
#define HW 4096
#define NKK 9

typedef __attribute__((ext_vector_type(8))) short bf16x8;
typedef __attribute__((ext_vector_type(4))) float f32x4;

__device__ __forceinline__ unsigned short f2bf(float f) {
  unsigned int u = __builtin_bit_cast(unsigned int, f);
  unsigned int r = u + 0x7FFFu + ((u >> 16) & 1u);
  return (unsigned short)(r >> 16);
}
__device__ __forceinline__ float bf2f(unsigned short h) {
  unsigned int u = ((unsigned int)h) << 16;
  return __builtin_bit_cast(float, u);
}

#define WB_ELEMS 589824    // 9*4*16*2*64*8  (main weights, fragment order)
#define WOB_ELEMS 147456   // 9*4*2*2*64*8   (offset-conv weights, oc padded to 32)
#define OFFPART_FLOATS (Bb * 18 * HW)   // one partial-offset buffer

// ---------------------------------------------------------------------------
// Prep: pack weights into exact MFMA B-fragment order (bf16).
// wB index [kk][cb][nt][ks][lane][e]: k = kk*256 + cb*64 + ks*32 + (lane>>4)*8 + e
//                                     oc = nt*16 + (lane&15)
// ---------------------------------------------------------------------------
__global__ __launch_bounds__(256) void prep_weights_kernel(
    const float* __restrict__ w,   // (256,256,3,3)
    const float* __restrict__ ow,  // (18,256,3,3)
    unsigned short* __restrict__ wBh, unsigned short* __restrict__ wBl,
    unsigned short* __restrict__ wOBh) {
  int i = blockIdx.x * 256 + threadIdx.x;
  if (i < WB_ELEMS) {
    int e = i & 7;
    int lane = (i >> 3) & 63;
    int ks = (i >> 9) & 1;
    int nt = (i >> 10) & 15;
    int cb = (i >> 14) & 3;
    int kk = i >> 16;
    int c = cb * 64 + ks * 32 + (lane >> 4) * 8 + e;
    int oc = nt * 16 + (lane & 15);
    float v = w[((size_t)oc * CIN + c) * 9 + kk];
    unsigned short hi = f2bf(v);
    wBh[i] = hi;
    wBl[i] = f2bf(v - bf2f(hi));
  } else {
    int j = i - WB_ELEMS;
    if (j < WOB_ELEMS) {
      int e = j & 7;
      int lane = (j >> 3) & 63;
      int ks = (j >> 9) & 1;
      int nt = (j >> 10) & 1;
      int cb = (j >> 11) & 3;
      int kk = j >> 13;
      int c = cb * 64 + ks * 32 + (lane >> 4) * 8 + e;
      int oc = nt * 16 + (lane & 15);
      float v = (oc < 18) ? ow[((size_t)oc * CIN + c) * 9 + kk] : 0.0f;
      wOBh[j] = f2bf(v);
    }
  }
}

// ---------------------------------------------------------------------------
// Offset conv via MFMA, channel-split for 2 blocks/CU.
// Grid 512: logical = (b,ho,chalf). chalf covers cb {0,1} or {2,3} (128 ch).
// Partial sums -> op0/op1; main kernel's phase 0 adds them. Bias in half 0.
// ---------------------------------------------------------------------------
__global__ __launch_bounds__(256) void offset_conv_kernel(
    const float* __restrict__ x,
    const unsigned short* __restrict__ wOBh,
    const float* __restrict__ ob,
    float* __restrict__ op0, float* __restrict__ op1) {
  __shared__ __align__(16) unsigned short smA[64 * 64];  // [px][c] bf16, swizzled

  const int tid = threadIdx.x;
  const int bid = blockIdx.x;
  const int logical = (bid & 7) * 64 + (bid >> 3);  // T1: 64 logical ids / XCD
  const int chalf = logical & 1;
  const int rowid = logical >> 1;   // b*64 + ho
  const int ho = rowid & 63;
  const int b  = rowid >> 6;
  const int lane = tid & 63;
  const int wv = tid >> 6;      // px m-tile
  const int px = tid & 63;
  const int c8g = tid >> 6;

  f32x4 acc[2];
  #pragma unroll
  for (int n = 0; n < 2; ++n)
    #pragma unroll
    for (int q = 0; q < 4; ++q) acc[n][q] = 0.0f;

  const float* xb = x + (size_t)b * CIN * HW;

  for (int kk = 0; kk < NKK; ++kk) {
    int ky = kk / 3, kx = kk % 3;
    int y = ho - 1 + ky;
    if (y < 0 || y >= Hh) continue;          // block-uniform: A all-zero
    int xx = px - 1 + kx;
    bool xv = (xx >= 0 && xx < Ww);
    int xxc = min(max(xx, 0), Ww - 1);
    const float* xrow = xb + (size_t)y * Ww + xxc;
    #pragma unroll
    for (int cb2 = 0; cb2 < 2; ++cb2) {
      int cb = chalf * 2 + cb2;
      __syncthreads();
      #pragma unroll
      for (int pass = 0; pass < 2; ++pass) {
        int c8 = c8g * 2 + pass;             // 0..7
        int cbase = cb * 64 + c8 * 8;
        unsigned int ph[4];
        #pragma unroll
        for (int j = 0; j < 4; ++j) {
          float v0 = xv ? xrow[(size_t)(cbase + 2 * j) * HW] : 0.0f;
          float v1 = xv ? xrow[(size_t)(cbase + 2 * j + 1) * HW] : 0.0f;
          ph[j] = (unsigned int)f2bf(v0) | ((unsigned int)f2bf(v1) << 16);
        }
        int boff = px * 128 + ((c8 ^ (px & 7)) * 16);
        *(uint4*)((char*)smA + boff) = make_uint4(ph[0], ph[1], ph[2], ph[3]);
      }
      __syncthreads();
      bf16x8 a[2];
      #pragma unroll
      for (int ks = 0; ks < 2; ++ks) {
        int pxa = wv * 16 + (lane & 15);
        int cg = ks * 4 + (lane >> 4);
        a[ks] = *(const bf16x8*)((const char*)smA + pxa * 128 + ((cg ^ (pxa & 7)) * 16));
      }
      #pragma unroll
      for (int nt = 0; nt < 2; ++nt) {
        #pragma unroll
        for (int ks = 0; ks < 2; ++ks) {
          size_t wi = ((((size_t)(kk * 4 + cb) * 2 + nt) * 2 + ks) * 64 + lane) * 8;
          bf16x8 bh = *(const bf16x8*)(wOBh + wi);
          acc[nt] = __builtin_amdgcn_mfma_f32_16x16x32_bf16(a[ks], bh, acc[nt], 0, 0, 0);
        }
      }
    }
  }
  // epilogue: D row=(lane>>4)*4+reg (px), col=lane&15 (oc)
  float* opart = chalf ? op1 : op0;
  #pragma unroll
  for (int nt = 0; nt < 2; ++nt) {
    int oc = nt * 16 + (lane & 15);
    if (oc < 18) {
      float bias = chalf ? 0.0f : ob[oc];
      float4 v4 = make_float4(acc[nt][0] + bias, acc[nt][1] + bias,
                              acc[nt][2] + bias, acc[nt][3] + bias);
      int pxo = wv * 16 + (lane >> 4) * 4;
      *(float4*)(opart + ((size_t)b * 18 + oc) * HW + (size_t)ho * Ww + pxo) = v4;
    }
  }
}

// ---------------------------------------------------------------------------
// Main: fused bilinear sample + MFMA GEMM, 3-term bf16 split.
// Block = 32 px x 256 oc, 512 threads = 8 waves (2 px-tiles x 4 oc-groups).
// Grid = 512 -> 2 blocks/CU: independent barrier domains hide gather latency.
// T1 swizzle: 64 logical blocks per XCD = 16 full rows of one batch.
// ---------------------------------------------------------------------------
__global__ __launch_bounds__(512) void deform_main_kernel(
    const float* __restrict__ x,
    const float* __restrict__ op0, const float* __restrict__ op1,
    const unsigned short* __restrict__ wBh, const unsigned short* __restrict__ wBl,
    float* __restrict__ out) {
  __shared__ __align__(16) int4   sm_idx[NKK][32];
  __shared__ __align__(16) float4 sm_w[NKK][32];
  __shared__ __align__(16) unsigned short smAh[2][32 * 64];
  __shared__ __align__(16) unsigned short smAl[2][32 * 64];

  const int tid = threadIdx.x;
  const int bid = blockIdx.x;
  const int logical = (bid & 7) * 64 + (bid >> 3);  // T1
  const int half = logical & 1;
  const int rowid = logical >> 1;   // b*64 + ho
  const int ho = rowid & 63;
  const int b  = rowid >> 6;
  const int p0 = half * 32;
  const int lane = tid & 63;
  const int wv = tid >> 6;
  const int m  = wv >> 2;       // px tile (16 px)
  const int og = wv & 3;        // oc group (64 oc)

  // ---- Phase 0: bilinear meta for 9 x 32 (kk, px); offset = op0 + op1 ----
  const float* ob0 = op0 + (size_t)b * 18 * HW + (size_t)ho * Ww + p0;
  const float* ob1 = op1 + (size_t)b * 18 * HW + (size_t)ho * Ww + p0;
  for (int i = tid; i < NKK * 32; i += 512) {
    int pp = i & 31;
    int kk = i >> 5;
    int ky = kk / 3, kx = kk % 3;
    float dy = ob0[(size_t)(2 * kk) * HW + pp] + ob1[(size_t)(2 * kk) * HW + pp];
    float dx = ob0[(size_t)(2 * kk + 1) * HW + pp] + ob1[(size_t)(2 * kk + 1) * HW + pp];
    float py = (float)(ho - 1 + ky) + dy;
    float pxf = (float)(p0 + pp - 1 + kx) + dx;
    float y0f = floorf(py), x0f = floorf(pxf);
    int y0 = (int)y0f, x0 = (int)x0f;
    float wy1 = py - y0f, wy0 = 1.0f - wy1;
    float wx1 = pxf - x0f, wx0 = 1.0f - wx1;
    int4 idx4; float4 w4;
    { bool v = (y0 >= 0 && y0 < Hh && x0 >= 0 && x0 < Ww);
      idx4.x = min(max(y0, 0), Hh - 1) * Ww + min(max(x0, 0), Ww - 1);
      w4.x = v ? wy0 * wx0 : 0.0f; }
    { int xs = x0 + 1; bool v = (y0 >= 0 && y0 < Hh && xs >= 0 && xs < Ww);
      idx4.y = min(max(y0, 0), Hh - 1) * Ww + min(max(xs, 0), Ww - 1);
      w4.y = v ? wy0 * wx1 : 0.0f; }
    { int ys = y0 + 1; bool v = (ys >= 0 && ys < Hh && x0 >= 0 && x0 < Ww);
      idx4.z = min(max(ys, 0), Hh - 1) * Ww + min(max(x0, 0), Ww - 1);
      w4.z = v ? wy1 * wx0 : 0.0f; }
    { int ys = y0 + 1, xs = x0 + 1; bool v = (ys >= 0 && ys < Hh && xs >= 0 && xs < Ww);
      idx4.w = min(max(ys, 0), Hh - 1) * Ww + min(max(xs, 0), Ww - 1);
      w4.w = v ? wy1 * wx1 : 0.0f; }
    sm_idx[kk][pp] = idx4;
    sm_w[kk][pp] = w4;
  }
  __syncthreads();

  f32x4 acc[4];
  #pragma unroll
  for (int n = 0; n < 4; ++n)
    #pragma unroll
    for (int q = 0; q < 4; ++q) acc[n][q] = 0.0f;

  const float* xb = x + (size_t)b * CIN * HW;
  const int spx = tid & 31;   // stage pixel
  const int sc4 = tid >> 5;   // stage 4-channel group (0..15)
  const int sboff = spx * 128 + (((sc4 >> 1) ^ (spx & 7)) * 16) + (sc4 & 1) * 8;

  // ---- prologue: stage chunk 0 (kk=0, cb=0) ----
  {
    int4 ip = sm_idx[0][spx];
    float4 wp = sm_w[0][spx];
    const float* xpB = xb + (size_t)(sc4 * 4) * HW;
    unsigned int ph[2], pl[2];
    #pragma unroll
    for (int j2 = 0; j2 < 2; ++j2) {
      const float* xp0 = xpB + (size_t)(2 * j2) * HW;
      const float* xp1 = xpB + (size_t)(2 * j2 + 1) * HW;
      float v0 = xp0[ip.x] * wp.x + xp0[ip.y] * wp.y + xp0[ip.z] * wp.z + xp0[ip.w] * wp.w;
      float v1 = xp1[ip.x] * wp.x + xp1[ip.y] * wp.y + xp1[ip.z] * wp.z + xp1[ip.w] * wp.w;
      unsigned short h0 = f2bf(v0), h1 = f2bf(v1);
      ph[j2] = (unsigned int)h0 | ((unsigned int)h1 << 16);
      pl[j2] = (unsigned int)f2bf(v0 - bf2f(h0)) | ((unsigned int)f2bf(v1 - bf2f(h1)) << 16);
    }
    *(uint2*)((char*)smAh[0] + sboff) = make_uint2(ph[0], ph[1]);
    *(uint2*)((char*)smAl[0] + sboff) = make_uint2(pl[0], pl[1]);
  }
  __syncthreads();

  for (int ch = 0; ch < 36; ++ch) {
    const int cur = ch & 1;
    // ---- issue gathers for chunk ch+1 (results land after MFMAs) ----
    float gg[4][4];
    int4 ipn; float4 wpn;
    const bool have_next = (ch + 1 < 36);
    if (have_next) {
      int kkn = (ch + 1) >> 2, cbn = (ch + 1) & 3;
      ipn = sm_idx[kkn][spx];
      wpn = sm_w[kkn][spx];
      const float* xpB = xb + (size_t)(cbn * 64 + sc4 * 4) * HW;
      #pragma unroll
      for (int j = 0; j < 4; ++j) {
        const float* xp = xpB + (size_t)j * HW;
        gg[j][0] = xp[ipn.x];
        gg[j][1] = xp[ipn.y];
        gg[j][2] = xp[ipn.z];
        gg[j][3] = xp[ipn.w];
      }
    }
    // ---- MFMAs for chunk ch from buffer cur ----
    {
      int kk = ch >> 2, cb = ch & 3;
      bf16x8 ah[2], al[2];
      #pragma unroll
      for (int ks = 0; ks < 2; ++ks) {
        int pxa = m * 16 + (lane & 15);
        int cg = ks * 4 + (lane >> 4);
        int aoff = pxa * 128 + ((cg ^ (pxa & 7)) * 16);
        ah[ks] = *(const bf16x8*)((const char*)smAh[cur] + aoff);
        al[ks] = *(const bf16x8*)((const char*)smAl[cur] + aoff);
      }
      #pragma unroll
      for (int nt = 0; nt < 4; ++nt) {
        #pragma unroll
        for (int ks = 0; ks < 2; ++ks) {
          size_t wi = ((((size_t)(kk * 4 + cb) * 16 + (og * 4 + nt)) * 2 + ks) * 64 + lane) * 8;
          bf16x8 bh = *(const bf16x8*)(wBh + wi);
          bf16x8 bl = *(const bf16x8*)(wBl + wi);
          acc[nt] = __builtin_amdgcn_mfma_f32_16x16x32_bf16(ah[ks], bh, acc[nt], 0, 0, 0);
          acc[nt] = __builtin_amdgcn_mfma_f32_16x16x32_bf16(al[ks], bh, acc[nt], 0, 0, 0);
          acc[nt] = __builtin_amdgcn_mfma_f32_16x16x32_bf16(ah[ks], bl, acc[nt], 0, 0, 0);
        }
      }
    }
    // ---- finish stage for chunk ch+1 into buffer cur^1 ----
    if (have_next) {
      unsigned int ph[2], pl[2];
      #pragma unroll
      for (int j2 = 0; j2 < 2; ++j2) {
        float v0 = gg[2 * j2][0] * wpn.x + gg[2 * j2][1] * wpn.y +
                   gg[2 * j2][2] * wpn.z + gg[2 * j2][3] * wpn.w;
        float v1 = gg[2 * j2 + 1][0] * wpn.x + gg[2 * j2 + 1][1] * wpn.y +
                   gg[2 * j2 + 1][2] * wpn.z + gg[2 * j2 + 1][3] * wpn.w;
        unsigned short h0 = f2bf(v0), h1 = f2bf(v1);
        ph[j2] = (unsigned int)h0 | ((unsigned int)h1 << 16);
        pl[j2] = (unsigned int)f2bf(v0 - bf2f(h0)) | ((unsigned int)f2bf(v1 - bf2f(h1)) << 16);
      }
      *(uint2*)((char*)smAh[cur ^ 1] + sboff) = make_uint2(ph[0], ph[1]);
      *(uint2*)((char*)smAl[cur ^ 1] + sboff) = make_uint2(pl[0], pl[1]);
    }
    __syncthreads();
  }

  // ---- epilogue: px = p0 + m*16 + (lane>>4)*4 + r ----
  #pragma unroll
  for (int nt = 0; nt < 4; ++nt) {
    int oc = og * 64 + nt * 16 + (lane & 15);
    int pxo = p0 + m * 16 + (lane >> 4) * 4;
    float4 v4 = make_float4(acc[nt][0], acc[nt][1], acc[nt][2], acc[nt][3]);
    *(float4*)(out + ((size_t)b * COUT + oc) * HW + (size_t)ho * Ww + pxo) = v4;
  }
}

// ---------------------------------------------------------------------------
extern "C" void kernel_launch(void* const* d_in, const int* in_sizes, int n_in,
                              void* d_out, int out_size, void* d_ws, size_t ws_size,
                              hipStream_t stream) {
  const float* x  = (const float*)d_in[0];   // (4,256,64,64)
  const float* ow = (const float*)d_in[1];   // (18,256,3,3)
  const float* ob = (const float*)d_in[2];   // (18,)
  const float* w  = (const float*)d_in[3];   // (256,256,3,3)
  float* out = (float*)d_out;                // (4,256,64,64)

  // ws layout: op0 | op1 (fp32 partial offsets) | wBh | wBl | wOBh  ~= 5.0 MB
  float* op0 = (float*)d_ws;
  float* op1 = op0 + OFFPART_FLOATS;
  unsigned short* wBh  = (unsigned short*)(op1 + OFFPART_FLOATS);
  unsigned short* wBl  = wBh + WB_ELEMS;
  unsigned short* wOBh = wBl + WB_ELEMS;

  hipLaunchKernelGGL(prep_weights_kernel, dim3((WB_ELEMS + WOB_ELEMS) / 256),
                     dim3(256), 0, stream, w, ow, wBh, wBl, wOBh);
  hipLaunchKernelGGL(offset_conv_kernel, dim3(Bb * Hh * 2), dim3(256),
                     0, stream, x, wOBh, ob, op0, op1);
  hipLaunchKernelGGL(deform_main_kernel, dim3(Bb * Hh * 2), dim3(512),
                     0, stream, x, op0, op1, wBh, wBl, out);
}